// Round 1
// 1153.650 us; speedup vs baseline: 1.0686x; 1.0686x over previous
//
#include <hip/hip_runtime.h>
#include <hip/hip_bf16.h>
#include <cstdint>
#include <cstddef>

static constexpr int NFEAT   = 512;
static constexpr int NHID    = 128;
static constexpr int NLAYERS = 6;
static constexpr int NCLASS  = 64;

typedef __bf16 bf16x8 __attribute__((ext_vector_type(8)));
typedef float  floatx4 __attribute__((ext_vector_type(4)));

static __device__ __forceinline__ uint16_t f2bf(float v){
    __hip_bfloat16 h = __float2bfloat16(v);
    return *reinterpret_cast<uint16_t*>(&h);
}

// ---------------- dtype sniffer (bf16 vs fp32 inputs) ----------------
__global__ void k_sniff(const uint16_t* __restrict__ x, int nwords, uint32_t* __restrict__ flag){
    int i = blockIdx.x*256 + threadIdx.x;
    if (i < nwords){
        uint16_t w = x[i];
        if ((w & 0x7F80u) == 0x7F80u) atomicOr(flag, 1u);
    }
}

// ---------------- diagnostic sentinel (ws too small) ----------------
__global__ void k_sentinel(uint16_t* out, int nel){
    int i = blockIdx.x*256 + threadIdx.x;
    if (i < nel) out[i] = 0x3E00u;   // bf16 0.125
}

// ---------------- CSR build ----------------
__global__ void k_zero(uint32_t* p, int n){
    int i = blockIdx.x*256 + threadIdx.x;
    if (i < n) p[i] = 0u;
}

__global__ void k_hist(const int* __restrict__ rows, uint32_t* __restrict__ deg, int nE){
    int e = blockIdx.x*256 + threadIdx.x;
    if (e < nE) atomicAdd(&deg[rows[e]], 1u);
}

__global__ __launch_bounds__(1024) void k_scan1(const uint32_t* __restrict__ deg,
                                                uint32_t* __restrict__ row_start,
                                                uint32_t* __restrict__ partial, int n){
    __shared__ uint32_t sh[1024];
    int tid = threadIdx.x;
    int i = blockIdx.x*1024 + tid;
    uint32_t v = (i < n) ? deg[i] : 0u;
    sh[tid] = v; __syncthreads();
    for (int off = 1; off < 1024; off <<= 1){
        uint32_t t = (tid >= off) ? sh[tid-off] : 0u;
        __syncthreads();
        sh[tid] += t;
        __syncthreads();
    }
    if (i < n) row_start[i+1] = sh[tid];
    if (tid == 1023) partial[blockIdx.x] = sh[1023];
}

__global__ __launch_bounds__(128) void k_scan2(uint32_t* partial, int nb){
    __shared__ uint32_t sh[128];
    int tid = threadIdx.x;
    uint32_t v = (tid < nb) ? partial[tid] : 0u;
    sh[tid] = v; __syncthreads();
    for (int off = 1; off < 128; off <<= 1){
        uint32_t t = (tid >= off) ? sh[tid-off] : 0u;
        __syncthreads();
        sh[tid] += t;
        __syncthreads();
    }
    if (tid < nb) partial[tid] = sh[tid] - v;
}

// scan3: finalize row_start and emit per-bucket base cursors (bcur[b] = row_start[b<<8])
__global__ __launch_bounds__(1024) void k_scan3(const uint32_t* __restrict__ deg,
                                                uint32_t* __restrict__ row_start,
                                                const uint32_t* __restrict__ partial,
                                                uint32_t* __restrict__ bcur,
                                                uint32_t* __restrict__ cursor, int n){
    int i = blockIdx.x*1024 + threadIdx.x;
    if (i < n){
        uint32_t rs = row_start[i+1] + partial[blockIdx.x];
        row_start[i+1] = rs;
        uint32_t start = rs - deg[i];           // == row_start[i]
        cursor[i] = start;                      // kept for fallback path
        if ((i & 255) == 0) bcur[i >> 8] = start;
        if (i == 0) row_start[0] = 0u;
    }
}

// ---- fallback scatter (only used if nbuck > 512; not expected for this problem) ----
__global__ void k_scatter(const int* __restrict__ rows, const int* __restrict__ cols,
                          const void* __restrict__ vals,
                          uint32_t* __restrict__ cursor, uint2* __restrict__ ep, int nE,
                          const uint32_t* __restrict__ flags){
    int e = blockIdx.x*256 + threadIdx.x;
    if (e < nE){
        int r = rows[e];
        uint32_t pos = atomicAdd(&cursor[r], 1u);
        float v;
        if (flags[0]) v = ((const float*)vals)[e];
        else          v = __bfloat162float(((const __hip_bfloat16*)vals)[e]);
        ep[pos] = make_uint2((uint32_t)cols[e], __float_as_uint(v));
    }
}

// ---- Pass A: bin edges by bucket (row>>8). Output grouped by bucket, L2-friendly
// write frontier (one hot tail line per bucket). epb[pos]=(col,val), rloc[pos]=row&255.
__global__ __launch_bounds__(256) void k_bin(
    const int* __restrict__ rows, const int* __restrict__ cols,
    const void* __restrict__ vals,
    uint32_t* __restrict__ bcur,
    uint2* __restrict__ epb, uint8_t* __restrict__ rloc,
    int nE, int nbuck, int epb_per_block,
    const uint32_t* __restrict__ flags)
{
    __shared__ uint32_t h[512];
    const int tid = threadIdx.x;
    const int e0 = blockIdx.x * epb_per_block;
    int e1 = e0 + epb_per_block; if (e1 > nE) e1 = nE;

    for (int b = tid; b < nbuck; b += 256) h[b] = 0u;
    __syncthreads();
    for (int e = e0 + tid; e < e1; e += 256){
        int r = rows[e];
        atomicAdd(&h[r >> 8], 1u);
    }
    __syncthreads();
    for (int b = tid; b < nbuck; b += 256){
        uint32_t c = h[b];
        h[b] = c ? atomicAdd(&bcur[b], c) : 0u;   // reserve contiguous range per (block,bucket)
    }
    __syncthreads();
    const int fp32 = (int)flags[0];
    for (int e = e0 + tid; e < e1; e += 256){
        int r = rows[e];
        uint32_t pos = atomicAdd(&h[r >> 8], 1u);
        float v;
        if (fp32) v = ((const float*)vals)[e];
        else      v = __bfloat162float(((const __hip_bfloat16*)vals)[e]);
        epb[pos] = make_uint2((uint32_t)cols[e], __float_as_uint(v));
        rloc[pos] = (uint8_t)(r & 255);
    }
}

// ---- Pass C: per-bucket CSR finalize. One block per bucket; reads the bucket's
// contiguous binned range and scatters within a ~32KB window (L2-local, full lines).
__global__ __launch_bounds__(256) void k_csr(
    const uint32_t* __restrict__ row_start,
    const uint2* __restrict__ epb, const uint8_t* __restrict__ rloc,
    uint2* __restrict__ ep, int n)
{
    __shared__ uint32_t curs[256];
    const int b = blockIdx.x;
    const int r0 = b << 8;
    const int tid = threadIdx.x;
    const int r = r0 + tid;
    curs[tid] = (r < n) ? row_start[r] : 0u;
    __syncthreads();
    int rend = r0 + 256; if (rend > n) rend = n;
    const uint32_t s = row_start[r0];
    const uint32_t e = row_start[rend];
    for (uint32_t i = s + tid; i < e; i += 256){
        uint2 rec = epb[i];
        uint32_t rl = rloc[i];
        uint32_t pos = atomicAdd(&curs[rl], 1u);
        ep[pos] = rec;
    }
}

// ---- fused weight transpose+canonicalize (single launch for all 7 tensors) ----
__global__ void k_transpose_all(const void* __restrict__ W0, const void* __restrict__ Wh,
                                const void* __restrict__ Wfc,
                                uint16_t* __restrict__ W0t, uint16_t* __restrict__ Wht,
                                uint16_t* __restrict__ Wfct,
                                const uint32_t* __restrict__ flags)
{
    const int idx = blockIdx.x*256 + threadIdx.x;
    const int T0 = NFEAT*NHID;              // 65536
    const int T1 = (NLAYERS-1)*NHID*NHID;   // 81920
    const int T2 = NLAYERS*NHID*NCLASS;     // 49152
    const int fp32 = (int)flags[0];
    if (idx < T0){
        uint16_t w = fp32 ? f2bf(((const float*)W0)[idx]) : ((const uint16_t*)W0)[idx];
        int k = idx / NHID, nn = idx - k*NHID;
        W0t[nn*NFEAT + k] = w;
    } else if (idx < T0 + T1){
        int j = idx - T0;
        uint16_t w = fp32 ? f2bf(((const float*)Wh)[j]) : ((const uint16_t*)Wh)[j];
        int l = j / (NHID*NHID); int jj = j - l*(NHID*NHID);
        int k = jj / NHID, nn = jj - k*NHID;
        Wht[l*NHID*NHID + nn*NHID + k] = w;
    } else if (idx < T0 + T1 + T2){
        int j = idx - T0 - T1;
        uint16_t w = fp32 ? f2bf(((const float*)Wfc)[j]) : ((const uint16_t*)Wfc)[j];
        int k = j / NCLASS, nn = j - k*NCLASS;
        Wfct[nn*(NLAYERS*NHID) + k] = w;
    }
}

// ---------------- generic MFMA GEMM (layer-0 and final accum) ----------------
// MODE 0: write bf16 C (ldc = NTILES*16).  MODE 1: f32 C += result.
template<int NTILES, int MODE>
__global__ __launch_bounds__(256) void k_gemm(
    const void* __restrict__ Aany, int lda,
    const uint16_t* __restrict__ Bt, int ldb, int K, int Mwaves,
    uint16_t* __restrict__ Cb, float* __restrict__ Cf,
    const uint32_t* __restrict__ flagsp)
{
    __shared__ uint16_t lds[NTILES*16*40];
    const int tid  = threadIdx.x;
    const int lane = tid & 63;
    const int gw   = blockIdx.x*4 + (tid >> 6);
    const bool active = gw < Mwaves;
    const int m = lane & 15, quad = lane >> 4;
    const long row0 = (long)gw * 16;
    const int afp32 = flagsp ? (int)flagsp[0] : 0;
    const uint16_t* A16 = (const uint16_t*)Aany;
    const float*    A32 = (const float*)Aany;

    floatx4 acc[NTILES];
#pragma unroll
    for (int i = 0; i < NTILES; i++) acc[i] = (floatx4){0.f,0.f,0.f,0.f};

    for (int kk = 0; kk < K; kk += 32){
        for (int idx = tid; idx < NTILES*16*4; idx += 256){
            int nn = idx >> 2, c = idx & 3;
            *(bf16x8*)&lds[nn*40 + c*8] = *(const bf16x8*)&Bt[(long)nn*ldb + kk + c*8];
        }
        __syncthreads();
        if (active){
            bf16x8 a;
            if (afp32){
                const float* p = &A32[(row0 + m)*lda + kk + quad*8];
                float4 f0 = *(const float4*)p;
                float4 f1 = *(const float4*)(p + 4);
                a[0]=(__bf16)f0.x; a[1]=(__bf16)f0.y; a[2]=(__bf16)f0.z; a[3]=(__bf16)f0.w;
                a[4]=(__bf16)f1.x; a[5]=(__bf16)f1.y; a[6]=(__bf16)f1.z; a[7]=(__bf16)f1.w;
            } else {
                a = *(const bf16x8*)&A16[(row0 + m)*lda + kk + quad*8];
            }
#pragma unroll
            for (int nt = 0; nt < NTILES; nt++){
                bf16x8 b = *(const bf16x8*)&lds[(nt*16 + m)*40 + quad*8];
                acc[nt] = __builtin_amdgcn_mfma_f32_16x16x32_bf16(a, b, acc[nt], 0, 0, 0);
            }
        }
        __syncthreads();
    }
    if (active){
#pragma unroll
        for (int nt = 0; nt < NTILES; nt++){
#pragma unroll
            for (int r = 0; r < 4; r++){
                long row = row0 + quad*4 + r;       // C/D: row = (lane>>4)*4 + reg
                int  col = nt*16 + m;               //      col = lane&15
                float v = acc[nt][r];
                if (MODE == 1) Cf[row*(NTILES*16) + col] += v;
                else           Cb[row*(NTILES*16) + col] = f2bf(v);
            }
        }
    }
}

// ---------------- fused layer GEMM: C1 = A@B1 (bf16), C2 (+)= A@B2 (f32) ----------------
__global__ __launch_bounds__(256) void k_gemm_fused(
    const uint16_t* __restrict__ A,
    const uint16_t* __restrict__ B1t,
    const uint16_t* __restrict__ B2t, int ldb2,
    uint16_t* __restrict__ C1, float* __restrict__ C2, int nchunks,
    int store_c2)
{
    __shared__ uint16_t lds[(128+64)*132];   // B1 rows then B2 rows, 132-elem pitch
    const int tid = threadIdx.x, lane = tid & 63;
    for (int idx = tid; idx < 128*16; idx += 256){
        int nn = idx >> 4, c = idx & 15;
        *(bf16x8*)&lds[nn*132 + c*8] = *(const bf16x8*)&B1t[nn*128 + c*8];
    }
    for (int idx = tid; idx < 64*16; idx += 256){
        int nn = idx >> 4, c = idx & 15;
        *(bf16x8*)&lds[(128+nn)*132 + c*8] = *(const bf16x8*)&B2t[(long)nn*ldb2 + c*8];
    }
    __syncthreads();

    const int m = lane & 15, quad = lane >> 4;
    const int nw = gridDim.x * 4;
    for (int chunk = blockIdx.x*4 + (tid >> 6); chunk < nchunks; chunk += nw){
        const long row0 = (long)chunk * 16;
        const uint16_t* Arow = &A[(row0 + m)*128 + quad*8];
        bf16x8 a[4];
#pragma unroll
        for (int ks = 0; ks < 4; ks++) a[ks] = *(const bf16x8*)&Arow[ks*32];

        floatx4 acc1[8], acc2[4];
#pragma unroll
        for (int i = 0; i < 8; i++) acc1[i] = (floatx4){0.f,0.f,0.f,0.f};
#pragma unroll
        for (int i = 0; i < 4; i++) acc2[i] = (floatx4){0.f,0.f,0.f,0.f};

#pragma unroll
        for (int ks = 0; ks < 4; ks++){
            const int kk = ks*32 + quad*8;
#pragma unroll
            for (int nt = 0; nt < 8; nt++){
                bf16x8 b = *(const bf16x8*)&lds[(nt*16 + m)*132 + kk];
                acc1[nt] = __builtin_amdgcn_mfma_f32_16x16x32_bf16(a[ks], b, acc1[nt], 0, 0, 0);
            }
#pragma unroll
            for (int nt = 0; nt < 4; nt++){
                bf16x8 b = *(const bf16x8*)&lds[(128 + nt*16 + m)*132 + kk];
                acc2[nt] = __builtin_amdgcn_mfma_f32_16x16x32_bf16(a[ks], b, acc2[nt], 0, 0, 0);
            }
        }
        // C1: bf16, paired-lane dword stores
#pragma unroll
        for (int nt = 0; nt < 8; nt++){
#pragma unroll
            for (int r = 0; r < 4; r++){
                long row = row0 + quad*4 + r;
                int  col = nt*16 + m;
                float v  = acc1[nt][r];
                float vn = __shfl_xor(v, 1);
                if ((m & 1) == 0){
                    uint32_t pk = (uint32_t)f2bf(v) | ((uint32_t)f2bf(vn) << 16);
                    *(uint32_t*)&C1[row*128 + col] = pk;
                }
            }
        }
        // C2: f32, paired-lane float2 store or RMW
#pragma unroll
        for (int nt = 0; nt < 4; nt++){
#pragma unroll
            for (int r = 0; r < 4; r++){
                long row = row0 + quad*4 + r;
                int  col = nt*16 + m;
                float v  = acc2[nt][r];
                float vn = __shfl_xor(v, 1);
                if ((m & 1) == 0){
                    float2* p = (float2*)&C2[row*64 + col];
                    if (store_c2){
                        float2 o; o.x = v; o.y = vn; *p = o;
                    } else {
                        float2 o = *p;
                        o.x += v; o.y += vn;
                        *p = o;
                    }
                }
            }
        }
    }
}

// ------- SpMM: out[row,:] = relu( sum_e val_e * tmp[col_e,:] ), 1 wave/row -------
__global__ __launch_bounds__(256) void k_spmm(
    const uint2* __restrict__ ep, const uint32_t* __restrict__ row_start,
    const uint32_t* __restrict__ tmp, uint16_t* __restrict__ out, int n)
{
    int t = blockIdx.x*256 + threadIdx.x;
    int gw = t >> 6, lane = t & 63;
    if (gw >= n) return;
    uint32_t s = row_start[gw], e = row_start[gw+1];
    float ax = 0.f, ay = 0.f;
    for (uint32_t base = s; base < e; base += 64){
        int cnt = (int)(e - base); if (cnt > 64) cnt = 64;
        uint2 d = (lane < cnt) ? ep[base + lane] : make_uint2(0u, 0u);
        int j = 0;
        for (; j + 4 <= cnt; j += 4){
            uint32_t c0 = __shfl(d.x, j+0); float v0 = __uint_as_float(__shfl(d.y, j+0));
            uint32_t c1 = __shfl(d.x, j+1); float v1 = __uint_as_float(__shfl(d.y, j+1));
            uint32_t c2 = __shfl(d.x, j+2); float v2 = __uint_as_float(__shfl(d.y, j+2));
            uint32_t c3 = __shfl(d.x, j+3); float v3 = __uint_as_float(__shfl(d.y, j+3));
            uint32_t p0 = tmp[(size_t)c0*64 + lane];
            uint32_t p1 = tmp[(size_t)c1*64 + lane];
            uint32_t p2 = tmp[(size_t)c2*64 + lane];
            uint32_t p3 = tmp[(size_t)c3*64 + lane];
            ax = fmaf(v0, __uint_as_float(p0 << 16), ax); ay = fmaf(v0, __uint_as_float(p0 & 0xffff0000u), ay);
            ax = fmaf(v1, __uint_as_float(p1 << 16), ax); ay = fmaf(v1, __uint_as_float(p1 & 0xffff0000u), ay);
            ax = fmaf(v2, __uint_as_float(p2 << 16), ax); ay = fmaf(v2, __uint_as_float(p2 & 0xffff0000u), ay);
            ax = fmaf(v3, __uint_as_float(p3 << 16), ax); ay = fmaf(v3, __uint_as_float(p3 & 0xffff0000u), ay);
        }
        for (; j < cnt; j++){
            uint32_t c = __shfl(d.x, j); float v = __uint_as_float(__shfl(d.y, j));
            uint32_t p = tmp[(size_t)c*64 + lane];
            ax = fmaf(v, __uint_as_float(p << 16), ax);
            ay = fmaf(v, __uint_as_float(p & 0xffff0000u), ay);
        }
    }
    ax = fmaxf(ax, 0.f); ay = fmaxf(ay, 0.f);
    uint32_t packed = ((uint32_t)f2bf(ay) << 16) | (uint32_t)f2bf(ax);
    *(uint32_t*)&out[(size_t)gw*128 + 2*lane] = packed;
}

// ---------------- log_softmax over 64 classes (+bias), 1 wave/row ----------------
__global__ __launch_bounds__(256) void k_logsoftmax(const float* __restrict__ logits,
                                                    const void* __restrict__ bias,
                                                    void* __restrict__ out, int n,
                                                    const uint32_t* __restrict__ flags){
    int t = blockIdx.x*256 + threadIdx.x;
    int row = t >> 6, lane = t & 63;
    if (row >= n) return;
    const int fp32 = (int)flags[0];
    float b = fp32 ? ((const float*)bias)[lane]
                   : __bfloat162float(((const __hip_bfloat16*)bias)[lane]);
    float x = logits[(size_t)row*64 + lane] + b;
    float mx = x;
    for (int off = 32; off; off >>= 1) mx = fmaxf(mx, __shfl_xor(mx, off));
    float ex = __expf(x - mx);
    float sum = ex;
    for (int off = 32; off; off >>= 1) sum += __shfl_xor(sum, off);
    float r = x - mx - __logf(sum);
    if (fp32) ((float*)out)[(size_t)row*64 + lane] = r;
    else      ((uint16_t*)out)[(size_t)row*64 + lane] = f2bf(r);
}

// ---------------- launch ----------------
extern "C" void kernel_launch(void* const* d_in, const int* in_sizes, int n_in,
                              void* d_out, int out_size, void* d_ws, size_t ws_size,
                              hipStream_t stream){
    const void* x    = d_in[0];
    const int* rows  = (const int*)d_in[1];
    const int* cols  = (const int*)d_in[2];
    const void* vals = d_in[3];
    const void* W0   = d_in[4];
    const void* Wh   = d_in[5];
    const void* Wfc  = d_in[6];
    const void* bfc  = d_in[7];

    const int n  = in_sizes[0] / NFEAT;    // 100000
    const int nE = in_sizes[1];            // 1.6M

    char* ws = (char*)d_ws;
    size_t off = 0;
    auto alloc = [&](size_t bytes)->char*{
        char* p = ws + off;
        off = (off + bytes + 255) & ~(size_t)255;
        return p;
    };
    uint32_t* flags     = (uint32_t*)alloc(256);
    uint32_t* deg       = (uint32_t*)alloc((size_t)n*4);
    uint32_t* row_start = (uint32_t*)alloc(((size_t)n+1)*4);
    uint32_t* cursor    = (uint32_t*)alloc((size_t)n*4);
    uint32_t* partial   = (uint32_t*)alloc(512);
    uint32_t* bcur      = (uint32_t*)alloc(2048);
    uint2*    ep        = (uint2*)   alloc((size_t)nE*8);
    uint16_t* W0t       = (uint16_t*)alloc((size_t)NFEAT*NHID*2);
    uint16_t* Wht       = (uint16_t*)alloc((size_t)(NLAYERS-1)*NHID*NHID*2);
    uint16_t* Wfct      = (uint16_t*)alloc((size_t)NCLASS*NLAYERS*NHID*2);  // [64][768]
    uint16_t* tmp       = (uint16_t*)alloc((size_t)n*NHID*2);
    uint16_t* hbuf      = (uint16_t*)alloc((size_t)n*NHID*2);
    float*    logits    = (float*)   alloc((size_t)n*NCLASS*4);

    if (ws_size < off){
        k_sentinel<<<(out_size+255)/256, 256, 0, stream>>>((uint16_t*)d_out, out_size);
        return;
    }

    hipMemsetAsync(flags, 0, 4, stream);
    const int NW = 1 << 20;
    k_sniff<<<NW/256, 256, 0, stream>>>((const uint16_t*)x, NW, flags);

    const int scanBlocks = (n + 1023)/1024;
    k_zero<<<(n+255)/256, 256, 0, stream>>>(deg, n);
    k_hist<<<(nE+255)/256, 256, 0, stream>>>(rows, deg, nE);
    k_scan1<<<scanBlocks, 1024, 0, stream>>>(deg, row_start, partial, n);
    k_scan2<<<1, 128, 0, stream>>>(partial, scanBlocks);
    k_scan3<<<scanBlocks, 1024, 0, stream>>>(deg, row_start, partial, bcur, cursor, n);

    // weight transposes (single launch)
    const int TTOT = NFEAT*NHID + (NLAYERS-1)*NHID*NHID + NLAYERS*NHID*NCLASS;
    k_transpose_all<<<(TTOT+255)/256, 256, 0, stream>>>(W0, Wh, Wfc, W0t, Wht, Wfct, flags);

    // CSR build: two-pass bucketed scatter. Binned intermediate aliases tmp
    // (safe: tmp written first by layer-0 GEMM, which runs after this on the stream).
    const int nbuck = (n + 255) >> 8;
    if (nbuck <= 512 && (size_t)n*NHID*2 >= (size_t)nE*9){
        uint2*   epb  = (uint2*)tmp;
        uint8_t* rloc = (uint8_t*)tmp + (size_t)nE*8;
        const int EPB = 2048;
        k_bin<<<(nE+EPB-1)/EPB, 256, 0, stream>>>(rows, cols, vals, bcur, epb, rloc,
                                                  nE, nbuck, EPB, flags);
        k_csr<<<nbuck, 256, 0, stream>>>(row_start, epb, rloc, ep, n);
    } else {
        k_scatter<<<(nE+255)/256, 256, 0, stream>>>(rows, cols, vals, cursor, ep, nE, flags);
    }

    const int Mwaves = n/16;                 // 6250
    const int gemmBlocks = (Mwaves + 3)/4;   // 1563
    const int rowBlocks  = (n*64 + 255)/256;
    const int fusedBlocks = 768;             // 3 blocks/CU (LDS-limited occupancy)

    // layer 0: tmp = x @ W0 ; h0 = relu(spmm(tmp))
    k_gemm<8,0><<<gemmBlocks, 256, 0, stream>>>(x, NFEAT, W0t, NFEAT, NFEAT, Mwaves, tmp, nullptr, flags);
    k_spmm<<<rowBlocks, 256, 0, stream>>>(ep, row_start, (const uint32_t*)tmp, hbuf, n);
    // layers 1..5: fused (tmp = h_{l-1}@Wh_{l-1}, logits (+)= h_{l-1}@Wfc_{l-1}), then spmm
    for (int l = 1; l < NLAYERS; l++){
        k_gemm_fused<<<fusedBlocks, 256, 0, stream>>>(hbuf, Wht + (l-1)*NHID*NHID,
                                                      Wfct + (l-1)*NHID, NLAYERS*NHID,
                                                      tmp, logits, Mwaves, (l == 1) ? 1 : 0);
        k_spmm<<<rowBlocks, 256, 0, stream>>>(ep, row_start, (const uint32_t*)tmp, hbuf, n);
    }
    // final: logits += h5 @ Wfc_5 ; out = log_softmax(logits + bfc)
    k_gemm<4,1><<<gemmBlocks, 256, 0, stream>>>(hbuf, NHID, Wfct + (NLAYERS-1)*NHID, NLAYERS*NHID,
                                                NHID, Mwaves, nullptr, logits, nullptr);
    k_logsoftmax<<<rowBlocks, 256, 0, stream>>>(logits, bfc, d_out, n, flags);
}

// Round 3
// 1114.136 us; speedup vs baseline: 1.1065x; 1.0355x over previous
//
#include <hip/hip_runtime.h>
#include <hip/hip_bf16.h>
#include <cstdint>
#include <cstddef>

static constexpr int NFEAT   = 512;
static constexpr int NHID    = 128;
static constexpr int NLAYERS = 6;
static constexpr int NCLASS  = 64;

typedef __bf16 bf16x8 __attribute__((ext_vector_type(8)));
typedef float  floatx4 __attribute__((ext_vector_type(4)));

static __device__ __forceinline__ uint16_t f2bf(float v){
    __hip_bfloat16 h = __float2bfloat16(v);
    return *reinterpret_cast<uint16_t*>(&h);
}

// ---------------- dtype sniffer (bf16 vs fp32 inputs) ----------------
__global__ void k_sniff(const uint16_t* __restrict__ x, int nwords, uint32_t* __restrict__ flag){
    int i = blockIdx.x*256 + threadIdx.x;
    if (i < nwords){
        uint16_t w = x[i];
        if ((w & 0x7F80u) == 0x7F80u) atomicOr(flag, 1u);
    }
}

// ---------------- diagnostic sentinel (ws too small) ----------------
__global__ void k_sentinel(uint16_t* out, int nel){
    int i = blockIdx.x*256 + threadIdx.x;
    if (i < nel) out[i] = 0x3E00u;   // bf16 0.125
}

// ---------------- CSR build ----------------
__global__ void k_hist(const int* __restrict__ rows, uint32_t* __restrict__ deg, int nE){
    int e = blockIdx.x*256 + threadIdx.x;
    if (e < nE) atomicAdd(&deg[rows[e]], 1u);
}

__global__ __launch_bounds__(1024) void k_scan1(const uint32_t* __restrict__ deg,
                                                uint32_t* __restrict__ row_start,
                                                uint32_t* __restrict__ partial, int n){
    __shared__ uint32_t sh[1024];
    int tid = threadIdx.x;
    int i = blockIdx.x*1024 + tid;
    uint32_t v = (i < n) ? deg[i] : 0u;
    sh[tid] = v; __syncthreads();
    for (int off = 1; off < 1024; off <<= 1){
        uint32_t t = (tid >= off) ? sh[tid-off] : 0u;
        __syncthreads();
        sh[tid] += t;
        __syncthreads();
    }
    if (i < n) row_start[i+1] = sh[tid];
    if (tid == 1023) partial[blockIdx.x] = sh[1023];
}

__global__ __launch_bounds__(128) void k_scan2(uint32_t* partial, int nb){
    __shared__ uint32_t sh[128];
    int tid = threadIdx.x;
    uint32_t v = (tid < nb) ? partial[tid] : 0u;
    sh[tid] = v; __syncthreads();
    for (int off = 1; off < 128; off <<= 1){
        uint32_t t = (tid >= off) ? sh[tid-off] : 0u;
        __syncthreads();
        sh[tid] += t;
        __syncthreads();
    }
    if (tid < nb) partial[tid] = sh[tid] - v;
}

// scan3: finalize row_start and emit per-bucket base cursors (bcur[b] = row_start[b<<8])
__global__ __launch_bounds__(1024) void k_scan3(const uint32_t* __restrict__ deg,
                                                uint32_t* __restrict__ row_start,
                                                const uint32_t* __restrict__ partial,
                                                uint32_t* __restrict__ bcur,
                                                uint32_t* __restrict__ cursor, int n){
    int i = blockIdx.x*1024 + threadIdx.x;
    if (i < n){
        uint32_t rs = row_start[i+1] + partial[blockIdx.x];
        row_start[i+1] = rs;
        uint32_t start = rs - deg[i];           // == row_start[i]
        cursor[i] = start;                      // kept for fallback path
        if ((i & 255) == 0) bcur[i >> 8] = start;
        if (i == 0) row_start[0] = 0u;
    }
}

// ---- fallback scatter (only used if nbuck > 512; not expected for this problem) ----
__global__ void k_scatter(const int* __restrict__ rows, const int* __restrict__ cols,
                          const void* __restrict__ vals,
                          uint32_t* __restrict__ cursor, uint2* __restrict__ ep, int nE,
                          const uint32_t* __restrict__ flags){
    int e = blockIdx.x*256 + threadIdx.x;
    if (e < nE){
        int r = rows[e];
        uint32_t pos = atomicAdd(&cursor[r], 1u);
        float v;
        if (flags[0]) v = ((const float*)vals)[e];
        else          v = __bfloat162float(((const __hip_bfloat16*)vals)[e]);
        ep[pos] = make_uint2((uint32_t)cols[e], __float_as_uint(v));
    }
}

// ---- Pass A: bin edges by bucket (row>>8). L2-friendly write frontier. ----
__global__ __launch_bounds__(256) void k_bin(
    const int* __restrict__ rows, const int* __restrict__ cols,
    const void* __restrict__ vals,
    uint32_t* __restrict__ bcur,
    uint2* __restrict__ epb, uint8_t* __restrict__ rloc,
    int nE, int nbuck, int epb_per_block,
    const uint32_t* __restrict__ flags)
{
    __shared__ uint32_t h[512];
    const int tid = threadIdx.x;
    const int e0 = blockIdx.x * epb_per_block;
    int e1 = e0 + epb_per_block; if (e1 > nE) e1 = nE;

    for (int b = tid; b < nbuck; b += 256) h[b] = 0u;
    __syncthreads();
    for (int e = e0 + tid; e < e1; e += 256){
        int r = rows[e];
        atomicAdd(&h[r >> 8], 1u);
    }
    __syncthreads();
    for (int b = tid; b < nbuck; b += 256){
        uint32_t c = h[b];
        h[b] = c ? atomicAdd(&bcur[b], c) : 0u;
    }
    __syncthreads();
    const int fp32 = (int)flags[0];
    for (int e = e0 + tid; e < e1; e += 256){
        int r = rows[e];
        uint32_t pos = atomicAdd(&h[r >> 8], 1u);
        float v;
        if (fp32) v = ((const float*)vals)[e];
        else      v = __bfloat162float(((const __hip_bfloat16*)vals)[e]);
        epb[pos] = make_uint2((uint32_t)cols[e], __float_as_uint(v));
        rloc[pos] = (uint8_t)(r & 255);
    }
}

// ---- Pass C: per-bucket CSR finalize (scatter within ~32KB L2-local window) ----
__global__ __launch_bounds__(256) void k_csr(
    const uint32_t* __restrict__ row_start,
    const uint2* __restrict__ epb, const uint8_t* __restrict__ rloc,
    uint2* __restrict__ ep, int n)
{
    __shared__ uint32_t curs[256];
    const int b = blockIdx.x;
    const int r0 = b << 8;
    const int tid = threadIdx.x;
    const int r = r0 + tid;
    curs[tid] = (r < n) ? row_start[r] : 0u;
    __syncthreads();
    int rend = r0 + 256; if (rend > n) rend = n;
    const uint32_t s = row_start[r0];
    const uint32_t e = row_start[rend];
    for (uint32_t i = s + tid; i < e; i += 256){
        uint2 rec = epb[i];
        uint32_t rl = rloc[i];
        uint32_t pos = atomicAdd(&curs[rl], 1u);
        ep[pos] = rec;
    }
}

// ---- fused weight transpose+canonicalize (single launch for all 7 tensors) ----
__global__ void k_transpose_all(const void* __restrict__ W0, const void* __restrict__ Wh,
                                const void* __restrict__ Wfc,
                                uint16_t* __restrict__ W0t, uint16_t* __restrict__ Wht,
                                uint16_t* __restrict__ Wfct,
                                const uint32_t* __restrict__ flags)
{
    const int idx = blockIdx.x*256 + threadIdx.x;
    const int T0 = NFEAT*NHID;              // 65536
    const int T1 = (NLAYERS-1)*NHID*NHID;   // 81920
    const int T2 = NLAYERS*NHID*NCLASS;     // 49152
    const int fp32 = (int)flags[0];
    if (idx < T0){
        uint16_t w = fp32 ? f2bf(((const float*)W0)[idx]) : ((const uint16_t*)W0)[idx];
        int k = idx / NHID, nn = idx - k*NHID;
        W0t[nn*NFEAT + k] = w;
    } else if (idx < T0 + T1){
        int j = idx - T0;
        uint16_t w = fp32 ? f2bf(((const float*)Wh)[j]) : ((const uint16_t*)Wh)[j];
        int l = j / (NHID*NHID); int jj = j - l*(NHID*NHID);
        int k = jj / NHID, nn = jj - k*NHID;
        Wht[l*NHID*NHID + nn*NHID + k] = w;
    } else if (idx < T0 + T1 + T2){
        int j = idx - T0 - T1;
        uint16_t w = fp32 ? f2bf(((const float*)Wfc)[j]) : ((const uint16_t*)Wfc)[j];
        int k = j / NCLASS, nn = j - k*NCLASS;
        Wfct[nn*(NLAYERS*NHID) + k] = w;
    }
}

// ---------------- generic MFMA GEMM (layer-0) ----------------
template<int NTILES, int MODE>
__global__ __launch_bounds__(256) void k_gemm(
    const void* __restrict__ Aany, int lda,
    const uint16_t* __restrict__ Bt, int ldb, int K, int Mwaves,
    uint16_t* __restrict__ Cb, float* __restrict__ Cf,
    const uint32_t* __restrict__ flagsp)
{
    __shared__ uint16_t lds[NTILES*16*40];
    const int tid  = threadIdx.x;
    const int lane = tid & 63;
    const int gw   = blockIdx.x*4 + (tid >> 6);
    const bool active = gw < Mwaves;
    const int m = lane & 15, quad = lane >> 4;
    const long row0 = (long)gw * 16;
    const int afp32 = flagsp ? (int)flagsp[0] : 0;
    const uint16_t* A16 = (const uint16_t*)Aany;
    const float*    A32 = (const float*)Aany;

    floatx4 acc[NTILES];
#pragma unroll
    for (int i = 0; i < NTILES; i++) acc[i] = (floatx4){0.f,0.f,0.f,0.f};

    for (int kk = 0; kk < K; kk += 32){
        for (int idx = tid; idx < NTILES*16*4; idx += 256){
            int nn = idx >> 2, c = idx & 3;
            *(bf16x8*)&lds[nn*40 + c*8] = *(const bf16x8*)&Bt[(long)nn*ldb + kk + c*8];
        }
        __syncthreads();
        if (active){
            bf16x8 a;
            if (afp32){
                const float* p = &A32[(row0 + m)*lda + kk + quad*8];
                float4 f0 = *(const float4*)p;
                float4 f1 = *(const float4*)(p + 4);
                a[0]=(__bf16)f0.x; a[1]=(__bf16)f0.y; a[2]=(__bf16)f0.z; a[3]=(__bf16)f0.w;
                a[4]=(__bf16)f1.x; a[5]=(__bf16)f1.y; a[6]=(__bf16)f1.z; a[7]=(__bf16)f1.w;
            } else {
                a = *(const bf16x8*)&A16[(row0 + m)*lda + kk + quad*8];
            }
#pragma unroll
            for (int nt = 0; nt < NTILES; nt++){
                bf16x8 b = *(const bf16x8*)&lds[(nt*16 + m)*40 + quad*8];
                acc[nt] = __builtin_amdgcn_mfma_f32_16x16x32_bf16(a, b, acc[nt], 0, 0, 0);
            }
        }
        __syncthreads();
    }
    if (active){
#pragma unroll
        for (int nt = 0; nt < NTILES; nt++){
#pragma unroll
            for (int r = 0; r < 4; r++){
                long row = row0 + quad*4 + r;       // C/D: row = (lane>>4)*4 + reg
                int  col = nt*16 + m;               //      col = lane&15
                float v = acc[nt][r];
                if (MODE == 1) Cf[row*(NTILES*16) + col] += v;
                else           Cb[row*(NTILES*16) + col] = f2bf(v);
            }
        }
    }
}

// ---- final GEMM: out = log_softmax(logits + h5@Wfc5 + bias) fused epilogue ----
__global__ __launch_bounds__(256) void k_gemm_final(
    const uint16_t* __restrict__ A,
    const uint16_t* __restrict__ Bt, int ldb, int Mwaves,
    const float* __restrict__ logits, const void* __restrict__ bias,
    void* __restrict__ outp, const uint32_t* __restrict__ flags)
{
    __shared__ uint16_t lds[4*16*40];
    const int tid  = threadIdx.x;
    const int lane = tid & 63;
    const int gw   = blockIdx.x*4 + (tid >> 6);
    const bool active = gw < Mwaves;
    const int m = lane & 15, quad = lane >> 4;
    const long row0 = (long)gw * 16;

    floatx4 acc[4];
#pragma unroll
    for (int i = 0; i < 4; i++) acc[i] = (floatx4){0.f,0.f,0.f,0.f};

    for (int kk = 0; kk < 128; kk += 32){
        for (int idx = tid; idx < 4*16*4; idx += 256){
            int nn = idx >> 2, c = idx & 3;
            *(bf16x8*)&lds[nn*40 + c*8] = *(const bf16x8*)&Bt[(long)nn*ldb + kk + c*8];
        }
        __syncthreads();
        if (active){
            bf16x8 a = *(const bf16x8*)&A[(row0 + m)*128 + kk + quad*8];
#pragma unroll
            for (int nt = 0; nt < 4; nt++){
                bf16x8 b = *(const bf16x8*)&lds[(nt*16 + m)*40 + quad*8];
                acc[nt] = __builtin_amdgcn_mfma_f32_16x16x32_bf16(a, b, acc[nt], 0, 0, 0);
            }
        }
        __syncthreads();
    }
    if (active){
        const int fp32 = (int)flags[0];
        float b[4];
#pragma unroll
        for (int nt = 0; nt < 4; nt++){
            int col = nt*16 + m;
            b[nt] = fp32 ? ((const float*)bias)[col]
                         : __bfloat162float(((const __hip_bfloat16*)bias)[col]);
        }
#pragma unroll
        for (int r = 0; r < 4; r++){
            long row = row0 + quad*4 + r;
            float v[4];
#pragma unroll
            for (int nt = 0; nt < 4; nt++){
                int col = nt*16 + m;
                v[nt] = logits[row*64 + col] + acc[nt][r] + b[nt];
            }
            float mx = fmaxf(fmaxf(v[0],v[1]), fmaxf(v[2],v[3]));
#pragma unroll
            for (int off = 1; off < 16; off <<= 1) mx = fmaxf(mx, __shfl_xor(mx, off));
            float sum = __expf(v[0]-mx)+__expf(v[1]-mx)+__expf(v[2]-mx)+__expf(v[3]-mx);
#pragma unroll
            for (int off = 1; off < 16; off <<= 1) sum += __shfl_xor(sum, off);
            float ls = mx + __logf(sum);
#pragma unroll
            for (int nt = 0; nt < 4; nt++){
                int col = nt*16 + m;
                float rr = v[nt] - ls;
                if (fp32) ((float*)outp)[row*64 + col] = rr;
                else      ((uint16_t*)outp)[row*64 + col] = f2bf(rr);
            }
        }
    }
}

// ---------------- fused layer GEMM: C1 = A@B1 (bf16), C2 (+)= A@B2 (f32) ----------------
__global__ __launch_bounds__(256) void k_gemm_fused(
    const uint16_t* __restrict__ A,
    const uint16_t* __restrict__ B1t,
    const uint16_t* __restrict__ B2t, int ldb2,
    uint16_t* __restrict__ C1, float* __restrict__ C2, int nchunks,
    int store_c2)
{
    __shared__ uint16_t lds[(128+64)*132];   // B1 rows then B2 rows, 132-elem pitch
    const int tid = threadIdx.x, lane = tid & 63;
    for (int idx = tid; idx < 128*16; idx += 256){
        int nn = idx >> 4, c = idx & 15;
        *(bf16x8*)&lds[nn*132 + c*8] = *(const bf16x8*)&B1t[nn*128 + c*8];
    }
    for (int idx = tid; idx < 64*16; idx += 256){
        int nn = idx >> 4, c = idx & 15;
        *(bf16x8*)&lds[(128+nn)*132 + c*8] = *(const bf16x8*)&B2t[(long)nn*ldb2 + c*8];
    }
    __syncthreads();

    const int m = lane & 15, quad = lane >> 4;
    const int nw = gridDim.x * 4;
    for (int chunk = blockIdx.x*4 + (tid >> 6); chunk < nchunks; chunk += nw){
        const long row0 = (long)chunk * 16;
        const uint16_t* Arow = &A[(row0 + m)*128 + quad*8];
        bf16x8 a[4];
#pragma unroll
        for (int ks = 0; ks < 4; ks++) a[ks] = *(const bf16x8*)&Arow[ks*32];

        floatx4 acc1[8], acc2[4];
#pragma unroll
        for (int i = 0; i < 8; i++) acc1[i] = (floatx4){0.f,0.f,0.f,0.f};
#pragma unroll
        for (int i = 0; i < 4; i++) acc2[i] = (floatx4){0.f,0.f,0.f,0.f};

#pragma unroll
        for (int ks = 0; ks < 4; ks++){
            const int kk = ks*32 + quad*8;
#pragma unroll
            for (int nt = 0; nt < 8; nt++){
                bf16x8 b = *(const bf16x8*)&lds[(nt*16 + m)*132 + kk];
                acc1[nt] = __builtin_amdgcn_mfma_f32_16x16x32_bf16(a[ks], b, acc1[nt], 0, 0, 0);
            }
#pragma unroll
            for (int nt = 0; nt < 4; nt++){
                bf16x8 b = *(const bf16x8*)&lds[(128 + nt*16 + m)*132 + kk];
                acc2[nt] = __builtin_amdgcn_mfma_f32_16x16x32_bf16(a[ks], b, acc2[nt], 0, 0, 0);
            }
        }
        // C1: bf16, paired-lane dword stores
#pragma unroll
        for (int nt = 0; nt < 8; nt++){
#pragma unroll
            for (int r = 0; r < 4; r++){
                long row = row0 + quad*4 + r;
                int  col = nt*16 + m;
                float v  = acc1[nt][r];
                float vn = __shfl_xor(v, 1);
                if ((m & 1) == 0){
                    uint32_t pk = (uint32_t)f2bf(v) | ((uint32_t)f2bf(vn) << 16);
                    *(uint32_t*)&C1[row*128 + col] = pk;
                }
            }
        }
        // C2: f32, paired-lane float2 store or RMW
#pragma unroll
        for (int nt = 0; nt < 4; nt++){
#pragma unroll
            for (int r = 0; r < 4; r++){
                long row = row0 + quad*4 + r;
                int  col = nt*16 + m;
                float v  = acc2[nt][r];
                float vn = __shfl_xor(v, 1);
                if ((m & 1) == 0){
                    float2* p = (float2*)&C2[row*64 + col];
                    if (store_c2){
                        float2 o; o.x = v; o.y = vn; *p = o;
                    } else {
                        float2 o = *p;
                        o.x += v; o.y += vn;
                        *p = o;
                    }
                }
            }
        }
    }
}

// ------- SpMM v3: quarter-wave edges. Each 16-lane quarter owns one edge and
// gathers its 256B row as dwordx4 (16B/lane). 16 edges per iteration, 4 loads
// in flight per wave. Cross-quarter shfl_xor reduce at the end. -------
__global__ __launch_bounds__(256) void k_spmm(
    const uint2* __restrict__ ep, const uint32_t* __restrict__ row_start,
    const uint32_t* __restrict__ tmp, uint16_t* __restrict__ out, int n)
{
    int t = blockIdx.x*256 + threadIdx.x;
    int gw = t >> 6, lane = t & 63;
    if (gw >= n) return;
    uint32_t s = row_start[gw], e = row_start[gw+1];
    const int q  = lane >> 4;     // quarter 0..3 (edge slot)
    const int fl = lane & 15;     // feature slot: features [8*fl, 8*fl+8)
    float acc[8];
#pragma unroll
    for (int i = 0; i < 8; i++) acc[i] = 0.f;

#define ACC8(P, V) { \
    acc[0] = fmaf(V, __uint_as_float((P).x << 16), acc[0]); \
    acc[1] = fmaf(V, __uint_as_float((P).x & 0xffff0000u), acc[1]); \
    acc[2] = fmaf(V, __uint_as_float((P).y << 16), acc[2]); \
    acc[3] = fmaf(V, __uint_as_float((P).y & 0xffff0000u), acc[3]); \
    acc[4] = fmaf(V, __uint_as_float((P).z << 16), acc[4]); \
    acc[5] = fmaf(V, __uint_as_float((P).z & 0xffff0000u), acc[5]); \
    acc[6] = fmaf(V, __uint_as_float((P).w << 16), acc[6]); \
    acc[7] = fmaf(V, __uint_as_float((P).w & 0xffff0000u), acc[7]); }

    for (uint32_t base = s; base < e; base += 64){
        int cnt = (int)(e - base); if (cnt > 64) cnt = 64;
        // padded edges have val=0, col=0 -> harmless gather of row 0 scaled by 0
        uint2 d = (lane < cnt) ? ep[base + lane] : make_uint2(0u, 0u);
        for (int j = 0; j < cnt; j += 16){
            uint32_t c0 = __shfl(d.x, j+q);    float v0 = __uint_as_float(__shfl(d.y, j+q));
            uint32_t c1 = __shfl(d.x, j+q+4);  float v1 = __uint_as_float(__shfl(d.y, j+q+4));
            uint32_t c2 = __shfl(d.x, j+q+8);  float v2 = __uint_as_float(__shfl(d.y, j+q+8));
            uint32_t c3 = __shfl(d.x, j+q+12); float v3 = __uint_as_float(__shfl(d.y, j+q+12));
            uint4 p0 = *(const uint4*)&tmp[(size_t)c0*64 + fl*4];
            uint4 p1 = *(const uint4*)&tmp[(size_t)c1*64 + fl*4];
            uint4 p2 = *(const uint4*)&tmp[(size_t)c2*64 + fl*4];
            uint4 p3 = *(const uint4*)&tmp[(size_t)c3*64 + fl*4];
            ACC8(p0, v0); ACC8(p1, v1); ACC8(p2, v2); ACC8(p3, v3);
        }
    }
#undef ACC8

    // combine the 4 quarters (same features, disjoint edge subsets)
#pragma unroll
    for (int i = 0; i < 8; i++){
        acc[i] += __shfl_xor(acc[i], 16);
        acc[i] += __shfl_xor(acc[i], 32);
    }
    if (q == 0){
        uint32_t w0 = (uint32_t)f2bf(fmaxf(acc[0],0.f)) | ((uint32_t)f2bf(fmaxf(acc[1],0.f)) << 16);
        uint32_t w1 = (uint32_t)f2bf(fmaxf(acc[2],0.f)) | ((uint32_t)f2bf(fmaxf(acc[3],0.f)) << 16);
        uint32_t w2 = (uint32_t)f2bf(fmaxf(acc[4],0.f)) | ((uint32_t)f2bf(fmaxf(acc[5],0.f)) << 16);
        uint32_t w3 = (uint32_t)f2bf(fmaxf(acc[6],0.f)) | ((uint32_t)f2bf(fmaxf(acc[7],0.f)) << 16);
        uint4 o = make_uint4(w0, w1, w2, w3);
        *(uint4*)&out[(size_t)gw*128 + fl*8] = o;
    }
}

// ---------------- launch ----------------
extern "C" void kernel_launch(void* const* d_in, const int* in_sizes, int n_in,
                              void* d_out, int out_size, void* d_ws, size_t ws_size,
                              hipStream_t stream){
    const void* x    = d_in[0];
    const int* rows  = (const int*)d_in[1];
    const int* cols  = (const int*)d_in[2];
    const void* vals = d_in[3];
    const void* W0   = d_in[4];
    const void* Wh   = d_in[5];
    const void* Wfc  = d_in[6];
    const void* bfc  = d_in[7];

    const int n  = in_sizes[0] / NFEAT;    // 100000
    const int nE = in_sizes[1];            // 1.6M

    char* ws = (char*)d_ws;
    size_t off = 0;
    auto alloc = [&](size_t bytes)->char*{
        char* p = ws + off;
        off = (off + bytes + 255) & ~(size_t)255;
        return p;
    };
    uint32_t* flags     = (uint32_t*)alloc(256);
    uint32_t* deg       = (uint32_t*)alloc((size_t)n*4);
    uint32_t* row_start = (uint32_t*)alloc(((size_t)n+1)*4);
    uint32_t* cursor    = (uint32_t*)alloc((size_t)n*4);
    uint32_t* partial   = (uint32_t*)alloc(512);
    uint32_t* bcur      = (uint32_t*)alloc(2048);
    uint2*    ep        = (uint2*)   alloc((size_t)nE*8);
    uint16_t* W0t       = (uint16_t*)alloc((size_t)NFEAT*NHID*2);
    uint16_t* Wht       = (uint16_t*)alloc((size_t)(NLAYERS-1)*NHID*NHID*2);
    uint16_t* Wfct      = (uint16_t*)alloc((size_t)NCLASS*NLAYERS*NHID*2);  // [64][768]
    uint16_t* tmp       = (uint16_t*)alloc((size_t)n*NHID*2);
    uint16_t* hbuf      = (uint16_t*)alloc((size_t)n*NHID*2);
    float*    logits    = (float*)   alloc((size_t)n*NCLASS*4);

    if (ws_size < off){
        k_sentinel<<<(out_size+255)/256, 256, 0, stream>>>((uint16_t*)d_out, out_size);
        return;
    }

    hipMemsetAsync(flags, 0, 4, stream);
    const int NW = 1 << 20;
    k_sniff<<<NW/256, 256, 0, stream>>>((const uint16_t*)x, NW, flags);

    const int scanBlocks = (n + 1023)/1024;
    hipMemsetAsync(deg, 0, (size_t)n*4, stream);
    k_hist<<<(nE+255)/256, 256, 0, stream>>>(rows, deg, nE);
    k_scan1<<<scanBlocks, 1024, 0, stream>>>(deg, row_start, partial, n);
    k_scan2<<<1, 128, 0, stream>>>(partial, scanBlocks);
    k_scan3<<<scanBlocks, 1024, 0, stream>>>(deg, row_start, partial, bcur, cursor, n);

    // weight transposes (single launch)
    const int TTOT = NFEAT*NHID + (NLAYERS-1)*NHID*NHID + NLAYERS*NHID*NCLASS;
    k_transpose_all<<<(TTOT+255)/256, 256, 0, stream>>>(W0, Wh, Wfc, W0t, Wht, Wfct, flags);

    // CSR build: two-pass bucketed scatter. Binned intermediate aliases tmp
    // (safe: tmp written first by layer-0 GEMM, which runs after this on the stream).
    const int nbuck = (n + 255) >> 8;
    if (nbuck <= 512 && (size_t)n*NHID*2 >= (size_t)nE*9){
        uint2*   epb  = (uint2*)tmp;
        uint8_t* rloc = (uint8_t*)tmp + (size_t)nE*8;
        const int EPB = 2048;
        k_bin<<<(nE+EPB-1)/EPB, 256, 0, stream>>>(rows, cols, vals, bcur, epb, rloc,
                                                  nE, nbuck, EPB, flags);
        k_csr<<<nbuck, 256, 0, stream>>>(row_start, epb, rloc, ep, n);
    } else {
        k_scatter<<<(nE+255)/256, 256, 0, stream>>>(rows, cols, vals, cursor, ep, nE, flags);
    }

    const int Mwaves = n/16;                 // 6250
    const int gemmBlocks = (Mwaves + 3)/4;   // 1563
    const int rowBlocks  = (n*64 + 255)/256;
    const int fusedBlocks = 768;             // 3 blocks/CU (LDS-limited occupancy)

    // layer 0: tmp = x @ W0 ; h0 = relu(spmm(tmp))
    k_gemm<8,0><<<gemmBlocks, 256, 0, stream>>>(x, NFEAT, W0t, NFEAT, NFEAT, Mwaves, tmp, nullptr, flags);
    k_spmm<<<rowBlocks, 256, 0, stream>>>(ep, row_start, (const uint32_t*)tmp, hbuf, n);
    // layers 1..5: fused (tmp = h_{l-1}@Wh_{l-1}, logits (+)= h_{l-1}@Wfc_{l-1}), then spmm
    for (int l = 1; l < NLAYERS; l++){
        k_gemm_fused<<<fusedBlocks, 256, 0, stream>>>(hbuf, Wht + (l-1)*NHID*NHID,
                                                      Wfct + (l-1)*NHID, NLAYERS*NHID,
                                                      tmp, logits, Mwaves, (l == 1) ? 1 : 0);
        k_spmm<<<rowBlocks, 256, 0, stream>>>(ep, row_start, (const uint32_t*)tmp, hbuf, n);
    }
    // final: out = log_softmax(logits + h5@Wfc5 + bias), fully fused
    k_gemm_final<<<gemmBlocks, 256, 0, stream>>>(hbuf, Wfct + (NLAYERS-1)*NHID, NLAYERS*NHID,
                                                 Mwaves, logits, bfc, d_out, flags);
}